// Round 8
// baseline (88.606 us; speedup 1.0000x reference)
//
#include <hip/hip_runtime.h>
#include <stdint.h>

#define IW 512
#define IH 512
#define NPLANES 48
#define TX 128
#define TY 32
#define INR (TY + 10)   // 42 input rows per tile
#define BUFW 144        // staged cols [tx-8, tx+136)
#define SLOTS 8         // LDS ring slots (DMA depth 5)

typedef float f32x2 __attribute__((ext_vector_type(2)));

typedef __attribute__((address_space(1))) const uint32_t guint_t;
typedef __attribute__((address_space(3))) uint32_t luint_t;

// counted vmcnt wait, literal N, full compiler memory fence
#define WAITVM_(n) asm volatile("s_waitcnt vmcnt(" #n ")" ::: "memory")
#define WAITVM(n) WAITVM_(n)

// ---- packed-f32 helpers (VOP3P) ----
static __device__ __forceinline__ f32x2 pk_mul(f32x2 a, f32x2 b) {
    f32x2 d; asm("v_pk_mul_f32 %0, %1, %2" : "=v"(d) : "v"(a), "v"(b)); return d;
}
// normal packed fma, weight broadcast pair from SGPRs
static __device__ __forceinline__ f32x2 pk_fma_s(f32x2 a, f32x2 w, f32x2 c) {
    f32x2 d; asm("v_pk_fma_f32 %0, %1, %2, %3" : "=v"(d) : "v"(a), "s"(w), "v"(c)); return d;
}
// both result lanes use src0.hi:  d = {a.y*w.x, a.y*w.y}
static __device__ __forceinline__ f32x2 pk_mul_bh(f32x2 a, f32x2 w) {
    f32x2 d; asm("v_pk_mul_f32 %0, %1, %2 op_sel:[1,0] op_sel_hi:[1,1]"
                 : "=v"(d) : "v"(a), "s"(w)); return d;
}
static __device__ __forceinline__ f32x2 pk_fma_bh(f32x2 a, f32x2 w, f32x2 c) {
    f32x2 d; asm("v_pk_fma_f32 %0, %1, %2, %3 op_sel:[1,0,0] op_sel_hi:[1,1,1]"
                 : "=v"(d) : "v"(a), "s"(w), "v"(c)); return d;
}
// both result lanes use src0.lo:  d += {a.x*w.x, a.x*w.y}
static __device__ __forceinline__ f32x2 pk_fma_bl(f32x2 a, f32x2 w, f32x2 c) {
    f32x2 d; asm("v_pk_fma_f32 %0, %1, %2, %3 op_sel:[0,0,0] op_sel_hi:[0,1,1]"
                 : "=v"(d) : "v"(a), "s"(w), "v"(c)); return d;
}
static __device__ __forceinline__ float rcp_fast(float x) {
    float d; asm("v_rcp_f32 %0, %1" : "=v"(d) : "v"(x)); return d;
}

__device__ __forceinline__ int refl(int c) {
    c = (c < 0) ? -c : c;
    return (c > IW - 1) ? (2 * (IW - 1) - c) : c;
}

// gaussian(11, 1.5)
#define W0 0.00102838f
#define W1 0.00759873f
#define W2 0.03600078f
#define W3 0.10936070f
#define W4 0.21300555f
#define W5 0.26601174f
#define W6 0.21300555f
#define W7 0.10936070f
#define W8 0.03600078f
#define W9 0.00759873f
#define W10 0.00102838f

// stage row HR5 (global) into LDS slot HR5&7
#define ISSUE_ROW(HR5)                                                          \
    {                                                                           \
        const int rr = refl(ty - 5 + (HR5));                                    \
        const int ws = (HR5) & 7;                                               \
        if (dmaok) {                                                            \
            __builtin_amdgcn_global_load_lds((guint_t*)(p1 + (size_t)rr * IW + gcol), \
                                             (luint_t*)&buf[ws][0][0], 16, 0, 0);     \
            __builtin_amdgcn_global_load_lds((guint_t*)(p2 + (size_t)rr * IW + gcol), \
                                             (luint_t*)&buf[ws][1][0], 16, 0, 0);     \
        }                                                                       \
    }

// read lane window of slot RS into a1/a2 (+ border reflect fixups)
#define READ_WINDOW(RS)                                                         \
    {                                                                           \
        const f32x2* bp1 = (const f32x2*)&buf[RS][0][2 * l + 2];                \
        const f32x2* bp2 = (const f32x2*)&buf[RS][1][2 * l + 2];                \
        _Pragma("unroll")                                                       \
        for (int i = 0; i < 7; ++i) { a1[i] = bp1[i]; a2[i] = bp2[i]; }         \
        if (tx == 0) {                                                          \
            _Pragma("unroll")                                                   \
            for (int i = 1; i <= 5; ++i) {                                      \
                const int j = 2 * l + 2 + i;                                    \
                if (j < 8) {                                                    \
                    const float v1 = buf[RS][0][16 - j];                        \
                    const float v2 = buf[RS][1][16 - j];                        \
                    if (i & 1) { a1[i >> 1].y = v1; a2[i >> 1].y = v2; }        \
                    else       { a1[i >> 1].x = v1; a2[i >> 1].x = v2; }        \
                }                                                               \
            }                                                                   \
        } else if (tx == IW - TX) {                                             \
            _Pragma("unroll")                                                   \
            for (int i = 8; i <= 12; ++i) {                                     \
                const int j = 2 * l + 2 + i;                                    \
                if (j >= 136) {                                                 \
                    const float v1 = buf[RS][0][270 - j];                       \
                    const float v2 = buf[RS][1][270 - j];                       \
                    if (i & 1) { a1[i >> 1].y = v1; a2[i >> 1].y = v2; }        \
                    else       { a1[i >> 1].x = v1; a2[i >> 1].x = v2; }        \
                }                                                               \
            }                                                                   \
        }                                                                       \
    }

// One input-row step, read-ahead pipelined: compute row HR from a1/a2 (loaded
// last body), issue DMA row HR+5, wait, prefetch row HR+1's window, vertical.
// JJ compile-time (acc slot index = fn(JJ)).
#define SSIM_STEP(JJ, HR, DO_ISSUE, WAITN, DO_READ)                             \
  {                                                                             \
    const int hr = (HR);                                                        \
    /* ---- horizontal 11-tap via op_sel broadcast fmas (row hr, in regs) ---- */ \
    f32x2 H0, H1, H2, H3, H4;                                                   \
    {   /* i = 0: only hi element A(1) contributes */                           \
        const f32x2 Q11 = pk_mul(a1[0], a1[0]);                                 \
        const f32x2 Q22 = pk_mul(a2[0], a2[0]);                                 \
        const f32x2 Q12 = pk_mul(a1[0], a2[0]);                                 \
        H0 = pk_mul_bh(a1[0], WH[0]);                                           \
        H1 = pk_mul_bh(a2[0], WH[0]);                                           \
        H2 = pk_mul_bh(Q11,  WH[0]);                                            \
        H3 = pk_mul_bh(Q22,  WH[0]);                                            \
        H4 = pk_mul_bh(Q12,  WH[0]);                                            \
    }                                                                           \
    _Pragma("unroll")                                                           \
    for (int i = 1; i <= 5; ++i) {                                              \
        const f32x2 Q11 = pk_mul(a1[i], a1[i]);                                 \
        const f32x2 Q22 = pk_mul(a2[i], a2[i]);                                 \
        const f32x2 Q12 = pk_mul(a1[i], a2[i]);                                 \
        H0 = pk_fma_bl(a1[i], WL[i], H0); H0 = pk_fma_bh(a1[i], WH[i], H0);     \
        H1 = pk_fma_bl(a2[i], WL[i], H1); H1 = pk_fma_bh(a2[i], WH[i], H1);     \
        H2 = pk_fma_bl(Q11,  WL[i], H2); H2 = pk_fma_bh(Q11,  WH[i], H2);       \
        H3 = pk_fma_bl(Q22,  WL[i], H3); H3 = pk_fma_bh(Q22,  WH[i], H3);       \
        H4 = pk_fma_bl(Q12,  WL[i], H4); H4 = pk_fma_bh(Q12,  WH[i], H4);       \
    }                                                                           \
    {   /* i = 6: only lo element A(12) contributes */                          \
        const f32x2 Q11 = pk_mul(a1[6], a1[6]);                                 \
        const f32x2 Q22 = pk_mul(a2[6], a2[6]);                                 \
        const f32x2 Q12 = pk_mul(a1[6], a2[6]);                                 \
        H0 = pk_fma_bl(a1[6], WL[6], H0);                                       \
        H1 = pk_fma_bl(a2[6], WL[6], H1);                                       \
        H2 = pk_fma_bl(Q11,  WL[6], H2);                                        \
        H3 = pk_fma_bl(Q22,  WL[6], H3);                                        \
        H4 = pk_fma_bl(Q12,  WL[6], H4);                                        \
    }                                                                           \
    /* ---- DMA issue + wait + prefetch next row's window ---- */               \
    if (DO_ISSUE) ISSUE_ROW(hr + 5);                                            \
    if (DO_READ) {                                                              \
        WAITVM(WAITN);                                                          \
        READ_WINDOW((hr + 1) & 7);                                              \
    }                                                                           \
    /* ---- vertical rolling accumulation ---- */                               \
    _Pragma("unroll")                                                           \
    for (int k = 0; k < 11; ++k) {                                              \
        const int o = hr - k;               /* uniform */                       \
        if (o >= 0 && o < TY) {                                                 \
            const int s = (((JJ) - k) % 11 + 11) % 11;  /* compile-time */      \
            const f32x2 w2 = {gw[k], gw[k]};                                    \
            acc[s][0] = pk_fma_s(H0, w2, acc[s][0]);                            \
            acc[s][1] = pk_fma_s(H1, w2, acc[s][1]);                            \
            acc[s][2] = pk_fma_s(H2, w2, acc[s][2]);                            \
            acc[s][3] = pk_fma_s(H3, w2, acc[s][3]);                            \
            acc[s][4] = pk_fma_s(H4, w2, acc[s][4]);                            \
        }                                                                       \
    }                                                                           \
    /* ---- output row o = hr-10 completes at this input row ---- */            \
    if (hr >= 10) {                                                             \
        const int o = hr - 10;                                                  \
        const int sc = ((JJ) + 1) % 11;       /* compile-time */                \
        const f32x2 mu1 = acc[sc][0], mu2 = acc[sc][1];                         \
        const f32x2 m11 = acc[sc][2], m22 = acc[sc][3], m12 = acc[sc][4];       \
        const f32x2 mu1s = mu1 * mu1, mu2s = mu2 * mu2, mu12 = mu1 * mu2;       \
        const f32x2 s1 = m11 - mu1s, s2 = m22 - mu2s, s12 = m12 - mu12;         \
        const f32x2 num = (2.f * mu12 + 1e-4f) * (2.f * s12 + 9e-4f);           \
        f32x2 den = (mu1s + mu2s + 1e-4f) * (s1 + s2 + 9e-4f);                  \
        den = den + 1e-12f;                                                     \
        f32x2 rd; rd.x = rcp_fast(den.x); rd.y = rcp_fast(den.y);               \
        const f32x2 res = num * rd;                                             \
        _Pragma("unroll")                                                       \
        for (int a = 0; a < 5; ++a) { acc[sc][a].x = 0.f; acc[sc][a].y = 0.f; } \
        *(f32x2*)&po[(size_t)(ty + o) * IW + tx + 2 * l] = res;                 \
    }                                                                           \
  }

__launch_bounds__(64, 2)
__global__ void ssim_kernel(const float* __restrict__ img1,
                            const float* __restrict__ img2,
                            float* __restrict__ out)
{
    __shared__ float buf[SLOTS][2][BUFW];   // 9216 B; slot stride 1152 B

    const int l  = threadIdx.x;          // 0..63
    const int tx = blockIdx.x * TX;
    const int ty = blockIdx.y * TY;
    const size_t pb = (size_t)blockIdx.z * (size_t)(IW * IH);
    const float* p1 = img1 + pb;
    const float* p2 = img2 + pb;
    float* po = out + pb;

    const float gw[11] = {W0,W1,W2,W3,W4,W5,W6,W7,W8,W9,W10};
    // pair i = {A(2i),A(2i+1)}; H.x = sum_{k=1..11} w_{k-1}A(k); H.y = sum_{k=2..12} w_{k-2}A(k)
    const f32x2 WH[6] = { {W0, 0.f}, {W2, W1}, {W4, W3}, {W6, W5}, {W8, W7}, {W10, W9} };
    const f32x2 WL[7] = { {0.f,0.f}, {W1, W0}, {W3, W2}, {W5, W4}, {W7, W6}, {W9, W8}, {0.f, W10} };

    // ---- DMA lane setup: lane l (<36) stages 16B at cols [gcol, gcol+4) ----
    const int gcol = tx - 8 + 4 * l;
    const bool dmaok = (l < 36) && (gcol >= 0) && (gcol < IW);

    // ---- prologue: DMA rows 0..4 into slots 0..4 (depth 5) ----
    #pragma unroll
    for (int pr = 0; pr < 5; ++pr) {
        ISSUE_ROW(pr)
    }

    // rolling vertical accumulators: [slot mod 11][array], packed over 2 owned cols
    f32x2 acc[11][5];
    #pragma unroll
    for (int s = 0; s < 11; ++s) {
        #pragma unroll
        for (int a = 0; a < 5; ++a) { acc[s][a].x = 0.f; acc[s][a].y = 0.f; }
    }

    // window registers for the CURRENT row (read-ahead pipeline)
    f32x2 a1[7], a2[7];
    // pre-read row 0 (8 of the 10 prologue loads may stay in flight)
    WAITVM(8);
    READ_WINDOW(0)

    // ---- main: hr = 0..32; issue row hr+5, prefetch window hr+1, vmcnt(8) ----
    for (int hrb = 0; hrb < 33; hrb += 11) {
        #pragma unroll
        for (int jj = 0; jj < 11; ++jj) {
            SSIM_STEP(jj, hrb + jj, 1, 8, 1)
        }
    }
    // ---- tail: hr = 33..41 compile-time; drain vmcnt 8,8,8,8,6,4,2,0 ----
    SSIM_STEP(0, 33, 1, 8, 1)
    SSIM_STEP(1, 34, 1, 8, 1)
    SSIM_STEP(2, 35, 1, 8, 1)
    SSIM_STEP(3, 36, 1, 8, 1)   // issues row 41, the last
    SSIM_STEP(4, 37, 0, 6, 1)
    SSIM_STEP(5, 38, 0, 4, 1)
    SSIM_STEP(6, 39, 0, 2, 1)
    SSIM_STEP(7, 40, 0, 0, 1)   // reads slot 41&7=1, all loads drained
    SSIM_STEP(8, 41, 0, 0, 0)   // compute-only
}

extern "C" void kernel_launch(void* const* d_in, const int* in_sizes, int n_in,
                              void* d_out, int out_size, void* d_ws, size_t ws_size,
                              hipStream_t stream) {
    const float* img1 = (const float*)d_in[0];
    const float* img2 = (const float*)d_in[1];
    float* out = (float*)d_out;
    dim3 grid(IW / TX, IH / TY, NPLANES);
    ssim_kernel<<<grid, dim3(64), 0, stream>>>(img1, img2, out);
}